// Round 5
// baseline (244.634 us; speedup 1.0000x reference)
//
#include <hip/hip_runtime.h>
#include <hip/hip_bf16.h>

#define NN 10000
#define TT 8
#define LL 3
#define NGRP 625     // 10000 / 16 exactly

typedef __bf16 bf16;
typedef __attribute__((ext_vector_type(8))) __bf16 bf16x8;
typedef __attribute__((ext_vector_type(4))) float f32x4;
typedef __attribute__((ext_vector_type(16))) float f32x16;

// v_rcp_f32 (1 instr) instead of IEEE divide — bf16-grade accuracy (verified r4).
__device__ __forceinline__ float sigf(float x) {
    return __builtin_amdgcn_rcpf(1.0f + __expf(-x));
}
__device__ __forceinline__ float tanhf_(float x) {
    return fmaf(2.0f, __builtin_amdgcn_rcpf(1.0f + __expf(-2.0f * x)), -1.0f);
}

// ---------------------------------------------------------------------------
// prep: repack LSTM weights into bf16 B-fragment order + combine biases.
// wts layout (bf16): [l][mat][kh][nt][n16][k32]
// ---------------------------------------------------------------------------
__global__ void prep_kernel(const float* __restrict__ W_ih, const float* __restrict__ W_hh,
                            const float* __restrict__ b_ih, const float* __restrict__ b_hh,
                            bf16* __restrict__ wts, float* __restrict__ bias) {
    int id = blockIdx.x * 256 + threadIdx.x;
    if (id < LL * 2 * 256 * 64) {
        int col = id & 63;
        int row = (id >> 6) & 255;
        int mat = (id >> 14) & 1;
        int l = id >> 15;
        const float* src = mat ? W_hh : W_ih;
        float w = src[(l * 256 + row) * 64 + col];
        int kh = col >> 5, nt = row >> 4, nn = row & 15, kk = col & 31;
        wts[((((l * 2 + mat) * 2 + kh) * 16 + nt) * 16 + nn) * 32 + kk] = (bf16)w;
    } else {
        int id2 = id - LL * 2 * 256 * 64;
        if (id2 < LL * 256) bias[id2] = b_ih[id2] + b_hh[id2];
    }
}

// ---------------------------------------------------------------------------
// fused conv+lstm: 625 blocks x 256 threads (4 waves); block owns 16 nodes,
// loops levels in-block (max-over-L in registers).
// conv stage: wave handles pairs {2wv, 2wv+1} x all 8 t (B-frags amortized),
// 32x32x16 MFMA (M = 2 nodes x 16 nbrs, K = C = 16 exact), feat -> LDS.
// lstm stage: r3 register-gate structure — wave wv owns gate tiles
// {wv, 4+wv, 8+wv, 12+wv} (all i/f/g/o for hidden cols [16wv,16wv+16)),
// all 16 weight frags in registers (64 VGPRs), 16 MFMAs + 1 barrier per step,
// rcp-based cell, h exchanged via tiny double-buffered LDS.
// ---------------------------------------------------------------------------
__global__ __launch_bounds__(256, 3) void fused_kernel(
    const float* __restrict__ X, const int* __restrict__ As,
    const float* __restrict__ conv_w, const float* __restrict__ conv_b,
    const bf16* __restrict__ wts, const float* __restrict__ bias,
    float* __restrict__ out) {
    __shared__ __align__(16) bf16 featL[TT][16][72];   // 18.4 KB
    __shared__ __align__(16) bf16 hlds[2][16][72];     // 4.6 KB

    const int tid = threadIdx.x;
    const int lane = tid & 63;
    const int wv = tid >> 6;        // 0..3
    const int c16 = lane & 15;
    const int q = lane >> 4;
    const int m = lane & 31;        // conv: A row = (node-in-pair)<<4 | nbr
    const int hh = lane >> 5;       // conv: k-half
    const int ch0 = hh * 8;
    const int nsub = m >> 4;
    const int kn = m & 15;
    const int node0 = blockIdx.x * 16;

    float ymax[TT][4];
#pragma unroll
    for (int t = 0; t < TT; ++t)
#pragma unroll
        for (int r = 0; r < 4; ++r) ymax[t][r] = -3.0e38f;
    float hfin[4], cfin[4];
#pragma unroll
    for (int r = 0; r < 4; ++r) { hfin[r] = -3.0e38f; cfin[r] = -3.0e38f; }

    for (int l = 0; l < LL; ++l) {
        __syncthreads();  // previous level's featL reads / hlds use complete

        // ================= conv stage (this level) =================
        bf16x8 B0, B1;
        {
            const float* w0 = conv_w + ((l * 64 + m) * 16 + ch0);
            f32x4 a = *(const f32x4*)w0, b = *(const f32x4*)(w0 + 4);
            const float* w1 = conv_w + ((l * 64 + 32 + m) * 16 + ch0);
            f32x4 c = *(const f32x4*)w1, d = *(const f32x4*)(w1 + 4);
#pragma unroll
            for (int j = 0; j < 4; ++j) {
                B0[j] = (bf16)a[j]; B0[4 + j] = (bf16)b[j];
                B1[j] = (bf16)c[j]; B1[4 + j] = (bf16)d[j];
            }
        }
        const float cb0 = conv_b[l * 64 + m];
        const float cb1 = conv_b[l * 64 + 32 + m];

        // 2 pairs x 8 t per wave, chunked as (1 pair, 4 t): loads batched.
#pragma unroll
        for (int c = 0; c < 4; ++c) {
            const int pc = 2 * wv + (c & 1);
            const int t0 = (c >> 1) * 4;
            const int gn = node0 + 2 * pc + nsub;

            int aidx[4];
#pragma unroll
            for (int j = 0; j < 4; ++j)
                aidx[j] = As[((long)(l * 8 + t0 + j) * NN + gn) * 16 + kn];
            f32x4 sv[4][2], gv[4][2];
#pragma unroll
            for (int j = 0; j < 4; ++j) {
                const float* sp = X + ((gn * 8 + t0 + j) * 16 + ch0);
                sv[j][0] = *(const f32x4*)sp;
                sv[j][1] = *(const f32x4*)(sp + 4);
            }
#pragma unroll
            for (int j = 0; j < 4; ++j) {
                const float* gp = X + (((long)aidx[j] * 8 + t0 + j) * 16 + ch0);
                gv[j][0] = *(const f32x4*)gp;
                gv[j][1] = *(const f32x4*)(gp + 4);
            }

#pragma unroll
            for (int j = 0; j < 4; ++j) {
                bf16x8 af;
#pragma unroll
                for (int k = 0; k < 4; ++k) {
                    af[k]     = (bf16)(gv[j][0][k] - sv[j][0][k]);
                    af[4 + k] = (bf16)(gv[j][1][k] - sv[j][1][k]);
                }
                f32x16 D0, D1;
#pragma unroll
                for (int k = 0; k < 16; ++k) { D0[k] = 0.0f; D1[k] = 0.0f; }
                D0 = __builtin_amdgcn_mfma_f32_32x32x16_bf16(af, B0, D0, 0, 0, 0);
                D1 = __builtin_amdgcn_mfma_f32_32x32x16_bf16(af, B1, D1, 0, 0, 0);

                // max over neighbors: node-sub0 = regs 0..7, node-sub1 = 8..15
                float v00 = D0[0], v01 = D1[0], v10 = D0[8], v11 = D1[8];
#pragma unroll
                for (int k = 1; k < 8; ++k) {
                    v00 = fmaxf(v00, D0[k]);     v01 = fmaxf(v01, D1[k]);
                    v10 = fmaxf(v10, D0[8 + k]); v11 = fmaxf(v11, D1[8 + k]);
                }
                v00 = fmaxf(v00, __shfl_xor(v00, 32));
                v01 = fmaxf(v01, __shfl_xor(v01, 32));
                v10 = fmaxf(v10, __shfl_xor(v10, 32));
                v11 = fmaxf(v11, __shfl_xor(v11, 32));

                const float sA = hh ? v10 : v00;   // cols [0,32)
                const float sB = hh ? v11 : v01;   // cols [32,64)
                featL[t0 + j][2 * pc + hh][m]      = (bf16)(sA + cb0);
                featL[t0 + j][2 * pc + hh][32 + m] = (bf16)(sB + cb1);
            }
        }

        // ================= LSTM weights (registers, 64 VGPRs) =================
        const bf16* wb = wts + l * 32768;
        const int fo = c16 * 32 + q * 8;
        bf16x8 Bx0[4], Bx1[4], Bh0[4], Bh1[4];
        float brg[4];
#pragma unroll
        for (int g = 0; g < 4; ++g) {
            const int nt = 4 * g + wv;
            Bx0[g] = *(const bf16x8*)(wb + (0 * 16 + nt) * 512 + fo);
            Bx1[g] = *(const bf16x8*)(wb + (1 * 16 + nt) * 512 + fo);
            Bh0[g] = *(const bf16x8*)(wb + (2 * 16 + nt) * 512 + fo);
            Bh1[g] = *(const bf16x8*)(wb + (3 * 16 + nt) * 512 + fo);
            brg[g] = bias[l * 256 + nt * 16 + c16];
        }
        float c_r[4];
#pragma unroll
        for (int r = 0; r < 4; ++r) c_r[r] = 0.0f;

        // ================= 8 recurrent steps =================
#pragma unroll
        for (int t = 0; t < TT; ++t) {
            __syncthreads();  // t=0: featL ready; t>0: h(t-1) visible

            bf16x8 ax0 = *(const bf16x8*)&featL[t][c16][q * 8];
            bf16x8 ax1 = *(const bf16x8*)&featL[t][c16][32 + q * 8];
            bf16x8 ah0, ah1;
            if (t > 0) {
                ah0 = *(const bf16x8*)&hlds[(t + 1) & 1][c16][q * 8];
                ah1 = *(const bf16x8*)&hlds[(t + 1) & 1][c16][32 + q * 8];
            }

            f32x4 acc[4];
#pragma unroll
            for (int g = 0; g < 4; ++g) {
                float b = brg[g];
                acc[g] = (f32x4){b, b, b, b};
                acc[g] = __builtin_amdgcn_mfma_f32_16x16x32_bf16(ax0, Bx0[g], acc[g], 0, 0, 0);
                acc[g] = __builtin_amdgcn_mfma_f32_16x16x32_bf16(ax1, Bx1[g], acc[g], 0, 0, 0);
                if (t > 0) {
                    acc[g] = __builtin_amdgcn_mfma_f32_16x16x32_bf16(ah0, Bh0[g], acc[g], 0, 0, 0);
                    acc[g] = __builtin_amdgcn_mfma_f32_16x16x32_bf16(ah1, Bh1[g], acc[g], 0, 0, 0);
                }
            }

            // cell: lane holds nodes q*4+r, hidden col wv*16+c16
#pragma unroll
            for (int r = 0; r < 4; ++r) {
                float iv = acc[0][r], fv = acc[1][r], gg = acc[2][r], ov = acc[3][r];
                float c = sigf(fv) * c_r[r] + sigf(iv) * tanhf_(gg);
                c_r[r] = c;
                float h = sigf(ov) * tanhf_(c);
                hlds[t & 1][q * 4 + r][wv * 16 + c16] = (bf16)h;
                ymax[t][r] = fmaxf(ymax[t][r], h);
                if (t == TT - 1) {
                    hfin[r] = fmaxf(hfin[r], h);
                    cfin[r] = fmaxf(cfin[r], c);
                }
            }
        }
    }

    // ================= final stores (each element written exactly once) ======
    const int col = wv * 16 + c16;
#pragma unroll
    for (int t = 0; t < TT; ++t)
#pragma unroll
        for (int r = 0; r < 4; ++r)
            out[((long)(node0 + q * 4 + r) * 8 + t) * 64 + col] = ymax[t][r];
    float* sh = out + (long)NN * 8 * 64;
    float* sc = sh + (long)NN * 64;
#pragma unroll
    for (int r = 0; r < 4; ++r) {
        sh[(long)(node0 + q * 4 + r) * 64 + col] = hfin[r];
        sc[(long)(node0 + q * 4 + r) * 64 + col] = cfin[r];
    }
}

extern "C" void kernel_launch(void* const* d_in, const int* in_sizes, int n_in,
                              void* d_out, int out_size, void* d_ws, size_t ws_size,
                              hipStream_t stream) {
    const float* X = (const float*)d_in[0];
    const int* As = (const int*)d_in[1];
    const float* conv_w = (const float*)d_in[4];
    const float* conv_b = (const float*)d_in[5];
    const float* W_ih = (const float*)d_in[6];
    const float* W_hh = (const float*)d_in[7];
    const float* b_ih = (const float*)d_in[8];
    const float* b_hh = (const float*)d_in[9];
    float* out = (float*)d_out;

    char* ws = (char*)d_ws;
    bf16* wts = (bf16*)ws;                      // 98,304 bf16 = 196,608 B
    float* bias = (float*)(ws + 196608);        // 768 f32

    hipLaunchKernelGGL(prep_kernel, dim3(387), dim3(256), 0, stream,
                       W_ih, W_hh, b_ih, b_hh, wts, bias);
    hipLaunchKernelGGL(fused_kernel, dim3(NGRP), dim3(256), 0, stream,
                       X, As, conv_w, conv_b, wts, bias, out);
}

// Round 6
// 175.198 us; speedup vs baseline: 1.3963x; 1.3963x over previous
//
#include <hip/hip_runtime.h>
#include <hip/hip_bf16.h>

#define NN 10000
#define TT 8
#define LL 3
#define NGRP 625     // 10000 / 16 exactly

typedef __bf16 bf16;
typedef __attribute__((ext_vector_type(8))) __bf16 bf16x8;
typedef __attribute__((ext_vector_type(4))) float f32x4;
typedef __attribute__((ext_vector_type(16))) float f32x16;

// v_rcp_f32 (1 instr) instead of IEEE divide — bf16-grade accuracy (verified r4).
__device__ __forceinline__ float sigf(float x) {
    return __builtin_amdgcn_rcpf(1.0f + __expf(-x));
}
__device__ __forceinline__ float tanhf_(float x) {
    return fmaf(2.0f, __builtin_amdgcn_rcpf(1.0f + __expf(-2.0f * x)), -1.0f);
}

// ---------------------------------------------------------------------------
// prep: repack LSTM weights into bf16 B-fragment order + combine biases.
// wts layout (bf16): [l][mat][kh][nt][n16][k32]
// ---------------------------------------------------------------------------
__global__ void prep_kernel(const float* __restrict__ W_ih, const float* __restrict__ W_hh,
                            const float* __restrict__ b_ih, const float* __restrict__ b_hh,
                            bf16* __restrict__ wts, float* __restrict__ bias) {
    int id = blockIdx.x * 256 + threadIdx.x;
    if (id < LL * 2 * 256 * 64) {
        int col = id & 63;
        int row = (id >> 6) & 255;
        int mat = (id >> 14) & 1;
        int l = id >> 15;
        const float* src = mat ? W_hh : W_ih;
        float w = src[(l * 256 + row) * 64 + col];
        int kh = col >> 5, nt = row >> 4, nn = row & 15, kk = col & 31;
        wts[((((l * 2 + mat) * 2 + kh) * 16 + nt) * 16 + nn) * 32 + kk] = (bf16)w;
    } else {
        int id2 = id - LL * 2 * 256 * 64;
        if (id2 < LL * 256) bias[id2] = b_ih[id2] + b_hh[id2];
    }
}

// ---------------------------------------------------------------------------
// fused conv+lstm: 625 blocks x 256 threads (4 waves); block owns 16 nodes,
// loops levels in-block (max-over-L in registers).
// conv stage: wave handles pairs {2wv, 2wv+1} x all 8 t (B-frags amortized),
// 32x32x16 MFMA (M = 2 nodes x 16 nbrs, K = C = 16 exact), feat -> LDS.
// Chunk loop is #pragma unroll 1: full unroll made the compiler pipeline all
// 4 chunks' batched loads (~272 VGPRs) -> scratch spills -> 480 MB HBM (r5).
// lstm stage: register-gate structure — wave wv owns gate tiles
// {wv, 4+wv, 8+wv, 12+wv}, 16 weight frags in registers (64 VGPRs),
// 16 MFMAs + 1 barrier per step, rcp cell, h via double-buffered LDS.
// ---------------------------------------------------------------------------
__global__ __launch_bounds__(256, 3) void fused_kernel(
    const float* __restrict__ X, const int* __restrict__ As,
    const float* __restrict__ conv_w, const float* __restrict__ conv_b,
    const bf16* __restrict__ wts, const float* __restrict__ bias,
    float* __restrict__ out) {
    __shared__ __align__(16) bf16 featL[TT][16][72];   // 18.4 KB
    __shared__ __align__(16) bf16 hlds[2][16][72];     // 4.6 KB

    const int tid = threadIdx.x;
    const int lane = tid & 63;
    const int wv = tid >> 6;        // 0..3
    const int c16 = lane & 15;
    const int q = lane >> 4;
    const int m = lane & 31;        // conv: A row = (node-in-pair)<<4 | nbr
    const int hh = lane >> 5;       // conv: k-half
    const int ch0 = hh * 8;
    const int nsub = m >> 4;
    const int kn = m & 15;
    const int node0 = blockIdx.x * 16;

    float ymax[TT][4];
#pragma unroll
    for (int t = 0; t < TT; ++t)
#pragma unroll
        for (int r = 0; r < 4; ++r) ymax[t][r] = -3.0e38f;
    float hfin[4], cfin[4];
#pragma unroll
    for (int r = 0; r < 4; ++r) { hfin[r] = -3.0e38f; cfin[r] = -3.0e38f; }

    for (int l = 0; l < LL; ++l) {
        __syncthreads();  // previous level's featL reads / hlds use complete

        // ================= conv stage (this level) =================
        bf16x8 B0, B1;
        {
            const float* w0 = conv_w + ((l * 64 + m) * 16 + ch0);
            f32x4 a = *(const f32x4*)w0, b = *(const f32x4*)(w0 + 4);
            const float* w1 = conv_w + ((l * 64 + 32 + m) * 16 + ch0);
            f32x4 c = *(const f32x4*)w1, d = *(const f32x4*)(w1 + 4);
#pragma unroll
            for (int j = 0; j < 4; ++j) {
                B0[j] = (bf16)a[j]; B0[4 + j] = (bf16)b[j];
                B1[j] = (bf16)c[j]; B1[4 + j] = (bf16)d[j];
            }
        }
        const float cb0 = conv_b[l * 64 + m];
        const float cb1 = conv_b[l * 64 + 32 + m];

        // 2 pairs x 8 t per wave, chunked as (1 pair, 4 t); loads batched
        // within a chunk only — DO NOT unroll (see header comment).
#pragma unroll 1
        for (int c = 0; c < 4; ++c) {
            const int pc = 2 * wv + (c & 1);
            const int t0 = (c >> 1) * 4;
            const int gn = node0 + 2 * pc + nsub;

            int aidx[4];
#pragma unroll
            for (int j = 0; j < 4; ++j)
                aidx[j] = As[((long)(l * 8 + t0 + j) * NN + gn) * 16 + kn];
            f32x4 sv[4][2], gv[4][2];
#pragma unroll
            for (int j = 0; j < 4; ++j) {
                const float* sp = X + ((gn * 8 + t0 + j) * 16 + ch0);
                sv[j][0] = *(const f32x4*)sp;
                sv[j][1] = *(const f32x4*)(sp + 4);
            }
#pragma unroll
            for (int j = 0; j < 4; ++j) {
                const float* gp = X + (((long)aidx[j] * 8 + t0 + j) * 16 + ch0);
                gv[j][0] = *(const f32x4*)gp;
                gv[j][1] = *(const f32x4*)(gp + 4);
            }

#pragma unroll
            for (int j = 0; j < 4; ++j) {
                bf16x8 af;
#pragma unroll
                for (int k = 0; k < 4; ++k) {
                    af[k]     = (bf16)(gv[j][0][k] - sv[j][0][k]);
                    af[4 + k] = (bf16)(gv[j][1][k] - sv[j][1][k]);
                }
                f32x16 D0, D1;
#pragma unroll
                for (int k = 0; k < 16; ++k) { D0[k] = 0.0f; D1[k] = 0.0f; }
                D0 = __builtin_amdgcn_mfma_f32_32x32x16_bf16(af, B0, D0, 0, 0, 0);
                D1 = __builtin_amdgcn_mfma_f32_32x32x16_bf16(af, B1, D1, 0, 0, 0);

                // max over neighbors: node-sub0 = regs 0..7, node-sub1 = 8..15
                float v00 = D0[0], v01 = D1[0], v10 = D0[8], v11 = D1[8];
#pragma unroll
                for (int k = 1; k < 8; ++k) {
                    v00 = fmaxf(v00, D0[k]);     v01 = fmaxf(v01, D1[k]);
                    v10 = fmaxf(v10, D0[8 + k]); v11 = fmaxf(v11, D1[8 + k]);
                }
                v00 = fmaxf(v00, __shfl_xor(v00, 32));
                v01 = fmaxf(v01, __shfl_xor(v01, 32));
                v10 = fmaxf(v10, __shfl_xor(v10, 32));
                v11 = fmaxf(v11, __shfl_xor(v11, 32));

                const float sA = hh ? v10 : v00;   // cols [0,32)
                const float sB = hh ? v11 : v01;   // cols [32,64)
                featL[t0 + j][2 * pc + hh][m]      = (bf16)(sA + cb0);
                featL[t0 + j][2 * pc + hh][32 + m] = (bf16)(sB + cb1);
            }
        }

        // ================= LSTM weights (registers, 64 VGPRs) =================
        const bf16* wb = wts + l * 32768;
        const int fo = c16 * 32 + q * 8;
        bf16x8 Bx0[4], Bx1[4], Bh0[4], Bh1[4];
        float brg[4];
#pragma unroll
        for (int g = 0; g < 4; ++g) {
            const int nt = 4 * g + wv;
            Bx0[g] = *(const bf16x8*)(wb + (0 * 16 + nt) * 512 + fo);
            Bx1[g] = *(const bf16x8*)(wb + (1 * 16 + nt) * 512 + fo);
            Bh0[g] = *(const bf16x8*)(wb + (2 * 16 + nt) * 512 + fo);
            Bh1[g] = *(const bf16x8*)(wb + (3 * 16 + nt) * 512 + fo);
            brg[g] = bias[l * 256 + nt * 16 + c16];
        }
        float c_r[4];
#pragma unroll
        for (int r = 0; r < 4; ++r) c_r[r] = 0.0f;

        // ================= 8 recurrent steps =================
#pragma unroll
        for (int t = 0; t < TT; ++t) {
            __syncthreads();  // t=0: featL ready; t>0: h(t-1) visible

            bf16x8 ax0 = *(const bf16x8*)&featL[t][c16][q * 8];
            bf16x8 ax1 = *(const bf16x8*)&featL[t][c16][32 + q * 8];
            bf16x8 ah0, ah1;
            if (t > 0) {
                ah0 = *(const bf16x8*)&hlds[(t + 1) & 1][c16][q * 8];
                ah1 = *(const bf16x8*)&hlds[(t + 1) & 1][c16][32 + q * 8];
            }

            f32x4 acc[4];
#pragma unroll
            for (int g = 0; g < 4; ++g) {
                float b = brg[g];
                acc[g] = (f32x4){b, b, b, b};
                acc[g] = __builtin_amdgcn_mfma_f32_16x16x32_bf16(ax0, Bx0[g], acc[g], 0, 0, 0);
                acc[g] = __builtin_amdgcn_mfma_f32_16x16x32_bf16(ax1, Bx1[g], acc[g], 0, 0, 0);
                if (t > 0) {
                    acc[g] = __builtin_amdgcn_mfma_f32_16x16x32_bf16(ah0, Bh0[g], acc[g], 0, 0, 0);
                    acc[g] = __builtin_amdgcn_mfma_f32_16x16x32_bf16(ah1, Bh1[g], acc[g], 0, 0, 0);
                }
            }

            // cell: lane holds nodes q*4+r, hidden col wv*16+c16
#pragma unroll
            for (int r = 0; r < 4; ++r) {
                float iv = acc[0][r], fv = acc[1][r], gg = acc[2][r], ov = acc[3][r];
                float c = sigf(fv) * c_r[r] + sigf(iv) * tanhf_(gg);
                c_r[r] = c;
                float h = sigf(ov) * tanhf_(c);
                hlds[t & 1][q * 4 + r][wv * 16 + c16] = (bf16)h;
                ymax[t][r] = fmaxf(ymax[t][r], h);
                if (t == TT - 1) {
                    hfin[r] = fmaxf(hfin[r], h);
                    cfin[r] = fmaxf(cfin[r], c);
                }
            }
        }
    }

    // ================= final stores (each element written exactly once) ======
    const int col = wv * 16 + c16;
#pragma unroll
    for (int t = 0; t < TT; ++t)
#pragma unroll
        for (int r = 0; r < 4; ++r)
            out[((long)(node0 + q * 4 + r) * 8 + t) * 64 + col] = ymax[t][r];
    float* sh = out + (long)NN * 8 * 64;
    float* sc = sh + (long)NN * 64;
#pragma unroll
    for (int r = 0; r < 4; ++r) {
        sh[(long)(node0 + q * 4 + r) * 64 + col] = hfin[r];
        sc[(long)(node0 + q * 4 + r) * 64 + col] = cfin[r];
    }
}

extern "C" void kernel_launch(void* const* d_in, const int* in_sizes, int n_in,
                              void* d_out, int out_size, void* d_ws, size_t ws_size,
                              hipStream_t stream) {
    const float* X = (const float*)d_in[0];
    const int* As = (const int*)d_in[1];
    const float* conv_w = (const float*)d_in[4];
    const float* conv_b = (const float*)d_in[5];
    const float* W_ih = (const float*)d_in[6];
    const float* W_hh = (const float*)d_in[7];
    const float* b_ih = (const float*)d_in[8];
    const float* b_hh = (const float*)d_in[9];
    float* out = (float*)d_out;

    char* ws = (char*)d_ws;
    bf16* wts = (bf16*)ws;                      // 98,304 bf16 = 196,608 B
    float* bias = (float*)(ws + 196608);        // 768 f32

    hipLaunchKernelGGL(prep_kernel, dim3(387), dim3(256), 0, stream,
                       W_ih, W_hh, b_ih, b_hh, wts, bias);
    hipLaunchKernelGGL(fused_kernel, dim3(NGRP), dim3(256), 0, stream,
                       X, As, conv_w, conv_b, wts, bias, out);
}

// Round 7
// 166.864 us; speedup vs baseline: 1.4661x; 1.0499x over previous
//
#include <hip/hip_runtime.h>
#include <hip/hip_bf16.h>

#define NN 10000
#define TT 8
#define LL 3
#define NGRP 625     // 10000 / 16 exactly

// out layout: ys [N][T][64] = 5,120,000 f32 | h [N][64] = 640,000 | c [N][64]
#define OUT_ELEMS 6400000
#define H_OFF 5120000
#define C_OFF 5760000

typedef __bf16 bf16;
typedef __attribute__((ext_vector_type(8))) __bf16 bf16x8;
typedef __attribute__((ext_vector_type(4))) float f32x4;
typedef __attribute__((ext_vector_type(16))) float f32x16;

// v_rcp_f32 (1 instr) instead of IEEE divide — bf16-grade accuracy (verified r4).
__device__ __forceinline__ float sigf(float x) {
    return __builtin_amdgcn_rcpf(1.0f + __expf(-x));
}
__device__ __forceinline__ float tanhf_(float x) {
    return fmaf(2.0f, __builtin_amdgcn_rcpf(1.0f + __expf(-2.0f * x)), -1.0f);
}

// ---------------------------------------------------------------------------
// prep: repack LSTM weights into bf16 B-fragment order + combine biases.
// wts layout (bf16): [l][mat][kh][nt][n16][k32]
// ---------------------------------------------------------------------------
__global__ void prep_kernel(const float* __restrict__ W_ih, const float* __restrict__ W_hh,
                            const float* __restrict__ b_ih, const float* __restrict__ b_hh,
                            bf16* __restrict__ wts, float* __restrict__ bias) {
    int id = blockIdx.x * 256 + threadIdx.x;
    if (id < LL * 2 * 256 * 64) {
        int col = id & 63;
        int row = (id >> 6) & 255;
        int mat = (id >> 14) & 1;
        int l = id >> 15;
        const float* src = mat ? W_hh : W_ih;
        float w = src[(l * 256 + row) * 64 + col];
        int kh = col >> 5, nt = row >> 4, nn = row & 15, kk = col & 31;
        wts[((((l * 2 + mat) * 2 + kh) * 16 + nt) * 16 + nn) * 32 + kk] = (bf16)w;
    } else {
        int id2 = id - LL * 2 * 256 * 64;
        if (id2 < LL * 256) bias[id2] = b_ih[id2] + b_hh[id2];
    }
}

// ---------------------------------------------------------------------------
// Shared device body: conv(level l) -> LDS feat -> 8 LSTM steps for 16 nodes.
// Results land in ymax/hfin/cfin (caller decides where they go).
// conv: 32x32x16 MFMA (M = 2 nodes x 16 nbrs, K = C = 16 exact), chunk loop
// MUST stay unroll 1 (full unroll pipelines ~272 VGPRs of loads -> scratch
// spill -> 480 MB HBM; measured r5).
// lstm: wave wv owns gate tiles {wv,4+wv,8+wv,12+wv}; 16 weight frags in
// registers (64 VGPRs); 16 MFMAs + 1 barrier per step; rcp cell.
// ---------------------------------------------------------------------------
__device__ __forceinline__ void level_body(
    int l, int node0, int tid,
    const float* __restrict__ X, const int* __restrict__ As,
    const float* __restrict__ conv_w, const float* __restrict__ conv_b,
    const bf16* __restrict__ wts, const float* __restrict__ bias,
    bf16 (*featL)[16][72], bf16 (*hlds)[16][72],
    float ymax[TT][4], float hfin[4], float cfin[4], bool accum) {
    const int lane = tid & 63;
    const int wv = tid >> 6;        // 0..3
    const int c16 = lane & 15;
    const int q = lane >> 4;
    const int m = lane & 31;        // conv: A row = (node-in-pair)<<4 | nbr
    const int hh = lane >> 5;       // conv: k-half
    const int ch0 = hh * 8;
    const int nsub = m >> 4;
    const int kn = m & 15;

    // ================= conv stage =================
    bf16x8 B0, B1;
    {
        const float* w0 = conv_w + ((l * 64 + m) * 16 + ch0);
        f32x4 a = *(const f32x4*)w0, b = *(const f32x4*)(w0 + 4);
        const float* w1 = conv_w + ((l * 64 + 32 + m) * 16 + ch0);
        f32x4 c = *(const f32x4*)w1, d = *(const f32x4*)(w1 + 4);
#pragma unroll
        for (int j = 0; j < 4; ++j) {
            B0[j] = (bf16)a[j]; B0[4 + j] = (bf16)b[j];
            B1[j] = (bf16)c[j]; B1[4 + j] = (bf16)d[j];
        }
    }
    const float cb0 = conv_b[l * 64 + m];
    const float cb1 = conv_b[l * 64 + 32 + m];

#pragma unroll 1
    for (int c = 0; c < 4; ++c) {
        const int pc = 2 * wv + (c & 1);
        const int t0 = (c >> 1) * 4;
        const int gn = node0 + 2 * pc + nsub;

        int aidx[4];
#pragma unroll
        for (int j = 0; j < 4; ++j)
            aidx[j] = As[((long)(l * 8 + t0 + j) * NN + gn) * 16 + kn];
        f32x4 sv[4][2], gv[4][2];
#pragma unroll
        for (int j = 0; j < 4; ++j) {
            const float* sp = X + ((gn * 8 + t0 + j) * 16 + ch0);
            sv[j][0] = *(const f32x4*)sp;
            sv[j][1] = *(const f32x4*)(sp + 4);
        }
#pragma unroll
        for (int j = 0; j < 4; ++j) {
            const float* gp = X + (((long)aidx[j] * 8 + t0 + j) * 16 + ch0);
            gv[j][0] = *(const f32x4*)gp;
            gv[j][1] = *(const f32x4*)(gp + 4);
        }

#pragma unroll
        for (int j = 0; j < 4; ++j) {
            bf16x8 af;
#pragma unroll
            for (int k = 0; k < 4; ++k) {
                af[k]     = (bf16)(gv[j][0][k] - sv[j][0][k]);
                af[4 + k] = (bf16)(gv[j][1][k] - sv[j][1][k]);
            }
            f32x16 D0, D1;
#pragma unroll
            for (int k = 0; k < 16; ++k) { D0[k] = 0.0f; D1[k] = 0.0f; }
            D0 = __builtin_amdgcn_mfma_f32_32x32x16_bf16(af, B0, D0, 0, 0, 0);
            D1 = __builtin_amdgcn_mfma_f32_32x32x16_bf16(af, B1, D1, 0, 0, 0);

            float v00 = D0[0], v01 = D1[0], v10 = D0[8], v11 = D1[8];
#pragma unroll
            for (int k = 1; k < 8; ++k) {
                v00 = fmaxf(v00, D0[k]);     v01 = fmaxf(v01, D1[k]);
                v10 = fmaxf(v10, D0[8 + k]); v11 = fmaxf(v11, D1[8 + k]);
            }
            v00 = fmaxf(v00, __shfl_xor(v00, 32));
            v01 = fmaxf(v01, __shfl_xor(v01, 32));
            v10 = fmaxf(v10, __shfl_xor(v10, 32));
            v11 = fmaxf(v11, __shfl_xor(v11, 32));

            const float sA = hh ? v10 : v00;   // cols [0,32)
            const float sB = hh ? v11 : v01;   // cols [32,64)
            featL[t0 + j][2 * pc + hh][m]      = (bf16)(sA + cb0);
            featL[t0 + j][2 * pc + hh][32 + m] = (bf16)(sB + cb1);
        }
    }

    // ================= LSTM weights (registers, 64 VGPRs) =================
    const bf16* wb = wts + l * 32768;
    const int fo = c16 * 32 + q * 8;
    bf16x8 Bx0[4], Bx1[4], Bh0[4], Bh1[4];
    float brg[4];
#pragma unroll
    for (int g = 0; g < 4; ++g) {
        const int nt = 4 * g + wv;
        Bx0[g] = *(const bf16x8*)(wb + (0 * 16 + nt) * 512 + fo);
        Bx1[g] = *(const bf16x8*)(wb + (1 * 16 + nt) * 512 + fo);
        Bh0[g] = *(const bf16x8*)(wb + (2 * 16 + nt) * 512 + fo);
        Bh1[g] = *(const bf16x8*)(wb + (3 * 16 + nt) * 512 + fo);
        brg[g] = bias[l * 256 + nt * 16 + c16];
    }
    float c_r[4];
#pragma unroll
    for (int r = 0; r < 4; ++r) c_r[r] = 0.0f;

    // ================= 8 recurrent steps =================
#pragma unroll
    for (int t = 0; t < TT; ++t) {
        __syncthreads();  // t=0: featL ready; t>0: h(t-1) visible

        bf16x8 ax0 = *(const bf16x8*)&featL[t][c16][q * 8];
        bf16x8 ax1 = *(const bf16x8*)&featL[t][c16][32 + q * 8];
        bf16x8 ah0, ah1;
        if (t > 0) {
            ah0 = *(const bf16x8*)&hlds[(t + 1) & 1][c16][q * 8];
            ah1 = *(const bf16x8*)&hlds[(t + 1) & 1][c16][32 + q * 8];
        }

        f32x4 acc[4];
#pragma unroll
        for (int g = 0; g < 4; ++g) {
            float b = brg[g];
            acc[g] = (f32x4){b, b, b, b};
            acc[g] = __builtin_amdgcn_mfma_f32_16x16x32_bf16(ax0, Bx0[g], acc[g], 0, 0, 0);
            acc[g] = __builtin_amdgcn_mfma_f32_16x16x32_bf16(ax1, Bx1[g], acc[g], 0, 0, 0);
            if (t > 0) {
                acc[g] = __builtin_amdgcn_mfma_f32_16x16x32_bf16(ah0, Bh0[g], acc[g], 0, 0, 0);
                acc[g] = __builtin_amdgcn_mfma_f32_16x16x32_bf16(ah1, Bh1[g], acc[g], 0, 0, 0);
            }
        }

        // cell: lane holds nodes q*4+r, hidden col wv*16+c16
#pragma unroll
        for (int r = 0; r < 4; ++r) {
            float iv = acc[0][r], fv = acc[1][r], gg = acc[2][r], ov = acc[3][r];
            float c = sigf(fv) * c_r[r] + sigf(iv) * tanhf_(gg);
            c_r[r] = c;
            float h = sigf(ov) * tanhf_(c);
            hlds[t & 1][q * 4 + r][wv * 16 + c16] = (bf16)h;
            ymax[t][r] = accum ? fmaxf(ymax[t][r], h) : h;
            if (t == TT - 1) {
                hfin[r] = accum ? fmaxf(hfin[r], h) : h;
                cfin[r] = accum ? fmaxf(cfin[r], c) : c;
            }
        }
    }
}

// ---------------------------------------------------------------------------
// Path A: level-split. grid = 3*625; block = (level, 16 nodes); writes its
// level's ys/h/c to a ws slab mirroring the out layout. 7.3 blocks/CU.
// ---------------------------------------------------------------------------
__global__ __launch_bounds__(256, 3) void fused_split_kernel(
    const float* __restrict__ X, const int* __restrict__ As,
    const float* __restrict__ conv_w, const float* __restrict__ conv_b,
    const bf16* __restrict__ wts, const float* __restrict__ bias,
    float* __restrict__ slabs) {
    __shared__ __align__(16) bf16 featL[TT][16][72];   // 18.4 KB
    __shared__ __align__(16) bf16 hlds[2][16][72];     // 4.6 KB

    const int tid = threadIdx.x;
    const int l = blockIdx.x % 3;
    const int grp = blockIdx.x / 3;
    const int node0 = grp * 16;

    float ymax[TT][4], hfin[4], cfin[4];
    level_body(l, node0, tid, X, As, conv_w, conv_b, wts, bias,
               featL, hlds, ymax, hfin, cfin, /*accum=*/false);

    float* slab = slabs + (long)l * OUT_ELEMS;
    const int lane = tid & 63;
    const int wv = tid >> 6;
    const int c16 = lane & 15;
    const int q = lane >> 4;
    const int col = wv * 16 + c16;
#pragma unroll
    for (int t = 0; t < TT; ++t)
#pragma unroll
        for (int r = 0; r < 4; ++r)
            slab[((long)(node0 + q * 4 + r) * 8 + t) * 64 + col] = ymax[t][r];
#pragma unroll
    for (int r = 0; r < 4; ++r) {
        slab[H_OFF + (long)(node0 + q * 4 + r) * 64 + col] = hfin[r];
        slab[C_OFF + (long)(node0 + q * 4 + r) * 64 + col] = cfin[r];
    }
}

// max over the 3 level slabs -> out. 1.6M f32x4, fully coalesced.
__global__ __launch_bounds__(256) void reduce_kernel(
    const float* __restrict__ slabs, float* __restrict__ out) {
    const long i = (long)blockIdx.x * 256 + threadIdx.x;   // f32x4 index
    const f32x4* s0 = (const f32x4*)slabs;
    const f32x4* s1 = (const f32x4*)(slabs + OUT_ELEMS);
    const f32x4* s2 = (const f32x4*)(slabs + 2L * OUT_ELEMS);
    f32x4 a = s0[i], b = s1[i], c = s2[i], d;
#pragma unroll
    for (int k = 0; k < 4; ++k) d[k] = fmaxf(fmaxf(a[k], b[k]), c[k]);
    ((f32x4*)out)[i] = d;
}

// ---------------------------------------------------------------------------
// Path B (fallback if ws too small): r6 structure — in-block level loop,
// direct out writes. Proven 97 us.
// ---------------------------------------------------------------------------
__global__ __launch_bounds__(256, 3) void fused_kernel(
    const float* __restrict__ X, const int* __restrict__ As,
    const float* __restrict__ conv_w, const float* __restrict__ conv_b,
    const bf16* __restrict__ wts, const float* __restrict__ bias,
    float* __restrict__ out) {
    __shared__ __align__(16) bf16 featL[TT][16][72];
    __shared__ __align__(16) bf16 hlds[2][16][72];

    const int tid = threadIdx.x;
    const int node0 = blockIdx.x * 16;

    float ymax[TT][4], hfin[4], cfin[4];
    for (int l = 0; l < LL; ++l) {
        __syncthreads();
        level_body(l, node0, tid, X, As, conv_w, conv_b, wts, bias,
                   featL, hlds, ymax, hfin, cfin, /*accum=*/(l > 0));
    }

    const int lane = tid & 63;
    const int wv = tid >> 6;
    const int c16 = lane & 15;
    const int q = lane >> 4;
    const int col = wv * 16 + c16;
#pragma unroll
    for (int t = 0; t < TT; ++t)
#pragma unroll
        for (int r = 0; r < 4; ++r)
            out[((long)(node0 + q * 4 + r) * 8 + t) * 64 + col] = ymax[t][r];
    float* sh = out + (long)H_OFF;
    float* sc = out + (long)C_OFF;
#pragma unroll
    for (int r = 0; r < 4; ++r) {
        sh[(long)(node0 + q * 4 + r) * 64 + col] = hfin[r];
        sc[(long)(node0 + q * 4 + r) * 64 + col] = cfin[r];
    }
}

extern "C" void kernel_launch(void* const* d_in, const int* in_sizes, int n_in,
                              void* d_out, int out_size, void* d_ws, size_t ws_size,
                              hipStream_t stream) {
    const float* X = (const float*)d_in[0];
    const int* As = (const int*)d_in[1];
    const float* conv_w = (const float*)d_in[4];
    const float* conv_b = (const float*)d_in[5];
    const float* W_ih = (const float*)d_in[6];
    const float* W_hh = (const float*)d_in[7];
    const float* b_ih = (const float*)d_in[8];
    const float* b_hh = (const float*)d_in[9];
    float* out = (float*)d_out;

    char* ws = (char*)d_ws;
    // slabs first (aligned), then wts, then bias
    const size_t slabs_bytes = (size_t)3 * OUT_ELEMS * 4;   // 76.8 MB
    const bool big_ws = ws_size >= slabs_bytes + 196608 + 4096;

    if (big_ws) {
        float* slabs = (float*)ws;
        bf16* wts = (bf16*)(ws + slabs_bytes);
        float* bias = (float*)(ws + slabs_bytes + 196608);
        hipLaunchKernelGGL(prep_kernel, dim3(387), dim3(256), 0, stream,
                           W_ih, W_hh, b_ih, b_hh, wts, bias);
        hipLaunchKernelGGL(fused_split_kernel, dim3(3 * NGRP), dim3(256), 0, stream,
                           X, As, conv_w, conv_b, wts, bias, slabs);
        hipLaunchKernelGGL(reduce_kernel, dim3(OUT_ELEMS / 4 / 256), dim3(256), 0, stream,
                           slabs, out);
    } else {
        bf16* wts = (bf16*)ws;
        float* bias = (float*)(ws + 196608);
        hipLaunchKernelGGL(prep_kernel, dim3(387), dim3(256), 0, stream,
                           W_ih, W_hh, b_ih, b_hh, wts, bias);
        hipLaunchKernelGGL(fused_kernel, dim3(NGRP), dim3(256), 0, stream,
                           X, As, conv_w, conv_b, wts, bias, out);
    }
}